// Round 1
// baseline (305.892 us; speedup 1.0000x reference)
//
#include <hip/hip_runtime.h>
#include <math.h>

#define NROWS 32768   // 8*4096 query rows
#define DIM   64
#define NCODE 4096
#define EPS_RMS 1.1920929e-07f
#define EPS_BN  1e-5f

// ws layout (floats):
// [0:64)                a[col]  = rsqrt(var+eps)*bn_w
// [64:128)              b[col]  = bn_b - mean*a
// [128 : 128+NCODE*DIM) cb (normalized codebook)
// [WS_CC : +NCODE)      cc[k] = sum(cb[k]^2)
// [WS_PART : +2*NROWS*2) (dist, idx) partials for the 2 K-splits
#define WS_A    0
#define WS_B    64
#define WS_CB   128
#define WS_CC   (128 + NCODE * DIM)
#define WS_PART (WS_CC + NCODE)

// out layout (floats):
// chunk0 z_q_st : [0, NROWS*DIM)
// chunk1 z_e    : [NROWS*DIM, 2*NROWS*DIM)
// chunk2 q      : [2*NROWS*DIM, 2*NROWS*DIM + NROWS)
// chunk3 z_q    : [2*NROWS*DIM + NROWS, ...)

__global__ __launch_bounds__(1024) void k_bnstats(const float* __restrict__ w,
                                                  const float* __restrict__ bnw,
                                                  const float* __restrict__ bnb,
                                                  float* __restrict__ ws) {
    __shared__ float s1[16][64];
    __shared__ float s2[16][64];
    int col = threadIdx.x & 63;
    int rg  = threadIdx.x >> 6;   // 0..15
    float s = 0.f, sq = 0.f;
    for (int r = rg; r < NCODE; r += 16) {
        float v = w[r * DIM + col];
        s += v; sq += v * v;
    }
    s1[rg][col] = s; s2[rg][col] = sq;
    __syncthreads();
    if (threadIdx.x < 64) {
        float ts = 0.f, tq = 0.f;
        #pragma unroll
        for (int i = 0; i < 16; i++) { ts += s1[i][col]; tq += s2[i][col]; }
        float mean = ts * (1.0f / NCODE);
        float var  = tq * (1.0f / NCODE) - mean * mean;
        float rstd = rsqrtf(var + EPS_BN);
        float a = rstd * bnw[col];
        float b = bnb[col] - mean * a;
        ws[WS_A + col] = a;
        ws[WS_B + col] = b;
    }
}

__global__ __launch_bounds__(256) void k_codebook(const float* __restrict__ w,
                                                  float* __restrict__ ws) {
    int lane = threadIdx.x & 63;
    int row  = blockIdx.x * 4 + (threadIdx.x >> 6);
    float a = ws[WS_A + lane];
    float b = ws[WS_B + lane];
    float h = w[row * DIM + lane] * a + b;
    float ss = h * h;
    #pragma unroll
    for (int m = 1; m < 64; m <<= 1) ss += __shfl_xor(ss, m);
    float r = rsqrtf(ss * (1.0f / DIM) + EPS_RMS);
    float c = h * r;
    ws[WS_CB + row * DIM + lane] = c;
    float cs = c * c;
    #pragma unroll
    for (int m = 1; m < 64; m <<= 1) cs += __shfl_xor(cs, m);
    if (lane == 0) ws[WS_CC + row] = cs;
}

// grid 512: bid>>1 = row block (128 rows), bid&1 = K split (2048 codes each)
__global__ __launch_bounds__(256) void k_main(const float* __restrict__ z,
                                              const float* __restrict__ ws,
                                              float* __restrict__ out) {
    __shared__ float zT[DIM][128];
    __shared__ float cbT[DIM][128];
    __shared__ float cct[128];

    const float* cb = ws + WS_CB;
    const float* cc = ws + WS_CC;
    float* part = (float*)ws + WS_PART;

    int bid    = blockIdx.x;
    int rowblk = bid >> 1;
    int split  = bid & 1;
    int tid    = threadIdx.x;

    // ---- stage z: RMS-normalize 128 rows, write z_e out, fill zT[d][row] ----
    {
        float* sred = &cbT[0][0];        // overlay scratch (cbT unused yet)
        float* srms = &cbT[0][0] + 256;
        int r  = tid & 127;
        int dg = tid >> 7;               // 0..1 -> d range dg*32..+31
        long grow = (long)rowblk * 128 + r;
        const float4* zp = (const float4*)(z + grow * DIM + dg * 32);
        float4 v[8];
        float ss = 0.f;
        #pragma unroll
        for (int i = 0; i < 8; i++) {
            v[i] = zp[i];
            ss += v[i].x * v[i].x + v[i].y * v[i].y + v[i].z * v[i].z + v[i].w * v[i].w;
        }
        sred[dg * 128 + r] = ss;
        __syncthreads();
        if (tid < 128) {
            float t = sred[tid] + sred[128 + tid];
            srms[tid] = rsqrtf(t * (1.0f / DIM) + EPS_RMS);
        }
        __syncthreads();
        float rms = srms[r];
        float4* oz = (float4*)(out + (size_t)NROWS * DIM + grow * DIM + dg * 32);
        #pragma unroll
        for (int i = 0; i < 8; i++) {
            v[i].x *= rms; v[i].y *= rms; v[i].z *= rms; v[i].w *= rms;
            zT[dg * 32 + i * 4 + 0][r] = v[i].x;
            zT[dg * 32 + i * 4 + 1][r] = v[i].y;
            zT[dg * 32 + i * 4 + 2][r] = v[i].z;
            zT[dg * 32 + i * 4 + 3][r] = v[i].w;
            if (split == 0) oz[i] = v[i];
        }
    }

    int tx = tid & 15;      // code group
    int ty = tid >> 4;      // row group
    float bd[2][4];
    int   bi[2][4];
    #pragma unroll
    for (int ri = 0; ri < 2; ri++)
        #pragma unroll
        for (int i = 0; i < 4; i++) { bd[ri][i] = 3.4e38f; bi[ri][i] = 0; }

    for (int p = 0; p < 16; p++) {
        int cbase = split * 2048 + p * 128;
        __syncthreads();   // prev compute done (also closes z staging)
        {   // stage cbT[d][code] transposed, + cc tile
            int c  = tid & 127;
            int dg = tid >> 7;
            const float4* cp = (const float4*)(cb + (size_t)(cbase + c) * DIM + dg * 32);
            #pragma unroll
            for (int i = 0; i < 8; i++) {
                float4 q = cp[i];
                cbT[dg * 32 + i * 4 + 0][c] = q.x;
                cbT[dg * 32 + i * 4 + 1][c] = q.y;
                cbT[dg * 32 + i * 4 + 2][c] = q.z;
                cbT[dg * 32 + i * 4 + 3][c] = q.w;
            }
            if (tid < 128) cct[tid] = cc[cbase + tid];
        }
        __syncthreads();

        float acc[2][4][2][4];
        #pragma unroll
        for (int ri = 0; ri < 2; ri++)
            #pragma unroll
            for (int i = 0; i < 4; i++)
                #pragma unroll
                for (int ci = 0; ci < 2; ci++)
                    #pragma unroll
                    for (int j = 0; j < 4; j++) acc[ri][i][ci][j] = 0.f;

        #pragma unroll 4
        for (int d = 0; d < DIM; d++) {
            float4 za = *(const float4*)&zT[d][ty * 4];
            float4 zb = *(const float4*)&zT[d][64 + ty * 4];
            float4 ca = *(const float4*)&cbT[d][tx * 4];
            float4 cv4 = *(const float4*)&cbT[d][64 + tx * 4];
            float zr[2][4] = {{za.x, za.y, za.z, za.w}, {zb.x, zb.y, zb.z, zb.w}};
            float cv[2][4] = {{ca.x, ca.y, ca.z, ca.w}, {cv4.x, cv4.y, cv4.z, cv4.w}};
            #pragma unroll
            for (int ri = 0; ri < 2; ri++)
                #pragma unroll
                for (int i = 0; i < 4; i++)
                    #pragma unroll
                    for (int ci = 0; ci < 2; ci++)
                        #pragma unroll
                        for (int j = 0; j < 4; j++)
                            acc[ri][i][ci][j] = fmaf(zr[ri][i], cv[ci][j], acc[ri][i][ci][j]);
        }

        // argmin update, ascending code order, strict < (first-min semantics)
        #pragma unroll
        for (int ri = 0; ri < 2; ri++)
            #pragma unroll
            for (int i = 0; i < 4; i++)
                #pragma unroll
                for (int ci = 0; ci < 2; ci++)
                    #pragma unroll
                    for (int j = 0; j < 4; j++) {
                        int code = cbase + ci * 64 + tx * 4 + j;
                        float cand = fmaf(-2.0f, acc[ri][i][ci][j], cct[ci * 64 + tx * 4 + j]);
                        if (cand < bd[ri][i]) { bd[ri][i] = cand; bi[ri][i] = code; }
                    }
    }

    // cross-lane reduce over the 16 tx lanes sharing each row group
    #pragma unroll
    for (int ri = 0; ri < 2; ri++)
        #pragma unroll
        for (int i = 0; i < 4; i++) {
            float d  = bd[ri][i];
            int  idx = bi[ri][i];
            #pragma unroll
            for (int m = 1; m < 16; m <<= 1) {
                float od = __shfl_xor(d, m);
                int   oi = __shfl_xor(idx, m);
                if (od < d || (od == d && oi < idx)) { d = od; idx = oi; }
            }
            if (tx == 0) {
                int row = rowblk * 128 + ri * 64 + ty * 4 + i;
                part[(size_t)(split * NROWS + row) * 2 + 0] = d;
                part[(size_t)(split * NROWS + row) * 2 + 1] = (float)idx;
            }
        }
}

__global__ __launch_bounds__(256) void k_final(const float* __restrict__ ws,
                                               float* __restrict__ out) {
    int t   = blockIdx.x * 256 + threadIdx.x;   // 0 .. NROWS*4
    int r   = t >> 2;
    int seg = t & 3;
    const float* part = ws + WS_PART;
    float d0 = part[(size_t)r * 2 + 0];
    float i0 = part[(size_t)r * 2 + 1];
    float d1 = part[(size_t)(NROWS + r) * 2 + 0];
    float i1 = part[(size_t)(NROWS + r) * 2 + 1];
    float fbest = (d1 < d0) ? i1 : i0;   // tie -> lower split = lower index
    int best = (int)fbest;
    const float4* src = (const float4*)(ws + WS_CB + (size_t)best * DIM + seg * 16);
    float4* o0 = (float4*)(out + (size_t)r * DIM + seg * 16);
    float4* o3 = (float4*)(out + (size_t)2 * NROWS * DIM + NROWS + (size_t)r * DIM + seg * 16);
    #pragma unroll
    for (int i = 0; i < 4; i++) { float4 v = src[i]; o0[i] = v; o3[i] = v; }
    if (seg == 0) out[(size_t)2 * NROWS * DIM + r] = fbest;
}

extern "C" void kernel_launch(void* const* d_in, const int* in_sizes, int n_in,
                              void* d_out, int out_size, void* d_ws, size_t ws_size,
                              hipStream_t stream) {
    const float* z   = (const float*)d_in[0];
    const float* w   = (const float*)d_in[1];
    const float* bnw = (const float*)d_in[2];
    const float* bnb = (const float*)d_in[3];
    float* out = (float*)d_out;
    float* ws  = (float*)d_ws;

    k_bnstats <<<1, 1024, 0, stream>>>(w, bnw, bnb, ws);
    k_codebook<<<NCODE / 4, 256, 0, stream>>>(w, ws);
    k_main    <<<(NROWS / 128) * 2, 256, 0, stream>>>(z, ws, out);
    k_final   <<<(NROWS * 4) / 256, 256, 0, stream>>>(ws, out);
}

// Round 2
// 84.366 us; speedup vs baseline: 3.6258x; 3.6258x over previous
//
#include <hip/hip_runtime.h>
#include <math.h>

#define NROWS 32768
#define DIM   64
#define NCODE 4096
#define EPS_RMS 1.1920929e-07f
#define EPS_BN  1e-5f

typedef _Float16 f16x8 __attribute__((ext_vector_type(8)));
typedef float    f32x4 __attribute__((ext_vector_type(4)));

// ws byte layout
#define WS_PS   0                        // partial sums   [64][64] f32 (16KB)
#define WS_PQ   16384                    // partial sumsq  [64][64] f32 (16KB)
#define WS_CC   32768                    // cc[4096] f32 (16KB)
#define WS_CB32 49152                    // cb fp32 [4096][64] (1MB)
#define WS_CH   (49152 + 1048576)        // cb f16 hi [4096][64] (512KB)
#define WS_CL   (WS_CH + 524288)         // cb f16 lo [4096][64] (512KB)

// out float offsets
#define OUT1 ((size_t)NROWS * DIM)           // z_e
#define OUT2 ((size_t)2 * NROWS * DIM)       // q
#define OUT3 (OUT2 + NROWS)                  // z_q

#define MFMA16(a, b, c) __builtin_amdgcn_mfma_f32_16x16x32_f16(a, b, c, 0, 0, 0)

__device__ __forceinline__ void async_copy16(void* lds, const void* g) {
    __builtin_amdgcn_global_load_lds(
        (const __attribute__((address_space(1))) unsigned int*)g,
        (__attribute__((address_space(3))) unsigned int*)lds, 16, 0, 0);
}

// ---- phase 1: per-column partial sums over 64-row slabs (deterministic, no atomics)
__global__ __launch_bounds__(256) void k_bn1(const float* __restrict__ w,
                                             char* __restrict__ wsb) {
    __shared__ float s1[4][64], s2[4][64];
    int lane = threadIdx.x & 63, v = threadIdx.x >> 6;
    long base = (long)blockIdx.x * 64 + v * 16;
    float s = 0.f, sq = 0.f;
    #pragma unroll
    for (int i = 0; i < 16; i++) {
        float x = w[(base + i) * DIM + lane];
        s += x; sq += x * x;
    }
    s1[v][lane] = s; s2[v][lane] = sq;
    __syncthreads();
    if (threadIdx.x < 64) {
        float ts = s1[0][lane] + s1[1][lane] + s1[2][lane] + s1[3][lane];
        float tq = s2[0][lane] + s2[1][lane] + s2[2][lane] + s2[3][lane];
        ((float*)(wsb + WS_PS))[blockIdx.x * 64 + lane] = ts;
        ((float*)(wsb + WS_PQ))[blockIdx.x * 64 + lane] = tq;
    }
}

// ---- phase 2: finalize stats (redundantly per block, deterministic), normalize codebook,
//      write cb32 / f16 hi / f16 lo / cc
__global__ __launch_bounds__(256) void k_cb(const float* __restrict__ w,
                                            const float* __restrict__ bnw,
                                            const float* __restrict__ bnb,
                                            char* __restrict__ wsb) {
    __shared__ float s1[4][64], s2[4][64], af[64], bf[64];
    int t = threadIdx.x, lane = t & 63, v = t >> 6;
    const float* ps = (const float*)(wsb + WS_PS);
    const float* pq = (const float*)(wsb + WS_PQ);
    float s = 0.f, sq = 0.f;
    #pragma unroll
    for (int b = 0; b < 16; b++) {
        s  += ps[(v * 16 + b) * 64 + lane];
        sq += pq[(v * 16 + b) * 64 + lane];
    }
    s1[v][lane] = s; s2[v][lane] = sq;
    __syncthreads();
    if (t < 64) {
        float ts = s1[0][lane] + s1[1][lane] + s1[2][lane] + s1[3][lane];
        float tq = s2[0][lane] + s2[1][lane] + s2[2][lane] + s2[3][lane];
        float mean = ts * (1.0f / NCODE);
        float var  = tq * (1.0f / NCODE) - mean * mean;
        float a = rsqrtf(var + EPS_BN) * bnw[lane];
        af[lane] = a;
        bf[lane] = bnb[lane] - mean * a;
    }
    __syncthreads();
    float a = af[lane], bb = bf[lane];
    float*     cb32 = (float*)(wsb + WS_CB32);
    _Float16*  chG  = (_Float16*)(wsb + WS_CH);
    _Float16*  clG  = (_Float16*)(wsb + WS_CL);
    float*     ccp  = (float*)(wsb + WS_CC);
    #pragma unroll
    for (int i = 0; i < 4; i++) {
        long row = (long)blockIdx.x * 16 + v * 4 + i;
        float x = w[row * DIM + lane];
        float h = fmaf(x, a, bb);
        float ss = h * h;
        #pragma unroll
        for (int m = 1; m < 64; m <<= 1) ss += __shfl_xor(ss, m);
        float rms = rsqrtf(ss * (1.0f / DIM) + EPS_RMS);
        float c = h * rms;
        cb32[row * DIM + lane] = c;
        _Float16 ch = (_Float16)c;
        chG[row * DIM + lane] = ch;
        clG[row * DIM + lane] = (_Float16)(c - (float)ch);
        float cs = c * c;
        #pragma unroll
        for (int m = 1; m < 64; m <<= 1) cs += __shfl_xor(cs, m);
        if (lane == 0) ccp[row] = cs;
    }
}

// ---- main: 64 rows/block, all 4096 codes, f16-split MFMA distance + fused argmin/gather
__global__ __launch_bounds__(256, 2) void k_main(const float* __restrict__ z,
                                                 const char* __restrict__ wsb,
                                                 float* __restrict__ out) {
    __shared__ __align__(16) unsigned char sm[32768];
    unsigned char* chT = sm;            // [128 codes][64 k] f16, 16KB (pass tiles)
    unsigned char* clT = sm + 16384;    // 16KB
    // prologue overlay: zh in sm[0:8192], zl in sm[8192:16384]

    const int tid  = threadIdx.x;
    const int lane = tid & 63;
    const int w    = tid >> 6;      // wave 0..3
    const int wr   = w >> 1;        // row half
    const int wc   = w & 1;         // code half
    const int l15  = lane & 15;
    const int l4   = lane >> 4;
    const long rowbase = (long)blockIdx.x * 64;

    const _Float16* chG  = (const _Float16*)(wsb + WS_CH);
    const _Float16* clG  = (const _Float16*)(wsb + WS_CL);
    const float*    ccG  = (const float*)(wsb + WS_CC);
    const float*    cb32 = (const float*)(wsb + WS_CB32);

    // ---- prologue: RMS-norm 64 rows of z, write z_e, split to f16 hi/lo in LDS
    {
        int r = tid >> 2, seg = tid & 3;
        const float* zrow = z + (rowbase + r) * DIM + seg * 16;
        float vv[16];
        float ss = 0.f;
        #pragma unroll
        for (int i = 0; i < 16; i++) { vv[i] = zrow[i]; ss += vv[i] * vv[i]; }
        ss += __shfl_xor(ss, 1);
        ss += __shfl_xor(ss, 2);
        float rms = rsqrtf(ss * (1.0f / DIM) + EPS_RMS);
        float* oz = out + OUT1 + (rowbase + r) * DIM + seg * 16;
        __align__(16) _Float16 hb[16], lb[16];
        #pragma unroll
        for (int i = 0; i < 16; i++) {
            float x = vv[i] * rms;
            oz[i] = x;
            _Float16 h = (_Float16)x;
            hb[i] = h;
            lb[i] = (_Float16)(x - (float)h);
        }
        unsigned char* zhp = sm + r * 128 + seg * 32;
        unsigned char* zlp = sm + 8192 + r * 128 + seg * 32;
        ((f16x8*)zhp)[0] = ((f16x8*)hb)[0];
        ((f16x8*)zhp)[1] = ((f16x8*)hb)[1];
        ((f16x8*)zlp)[0] = ((f16x8*)lb)[0];
        ((f16x8*)zlp)[1] = ((f16x8*)lb)[1];
    }
    __syncthreads();

    // ---- load A fragments (z) to registers: 2 rowsubs x 2 kchunks, hi+lo
    f16x8 ah[2][2], al[2][2];
    #pragma unroll
    for (int s = 0; s < 2; s++)
        #pragma unroll
        for (int c = 0; c < 2; c++) {
            int arow = wr * 32 + s * 16 + l15;
            ah[s][c] = *(const f16x8*)(sm + arow * 128 + c * 64 + l4 * 16);
            al[s][c] = *(const f16x8*)(sm + 8192 + arow * 128 + c * 64 + l4 * 16);
        }
    __syncthreads();   // LDS now free for codebook tiles

    float bd[2][4];
    int   bix[2][4];
    #pragma unroll
    for (int s = 0; s < 2; s++)
        #pragma unroll
        for (int r = 0; r < 4; r++) { bd[s][r] = 3.4e38f; bix[s][r] = 0; }

    for (int p = 0; p < 32; ++p) {
        int cbase = p * 128;
        // stage 128-code tile: hi+lo, pre-swizzled global source -> linear LDS dest
        #pragma unroll
        for (int i = 0; i < 4; i++) {
            int B = w * 4096 + i * 1024 + lane * 16;   // LDS linear byte this lane fills
            int code = B >> 7;
            int sp   = (B >> 4) & 7;
            long ge = (long)(cbase + code) * DIM + (long)((sp ^ (code & 7)) * 8);
            async_copy16(chT + w * 4096 + i * 1024, chG + ge);
            async_copy16(clT + w * 4096 + i * 1024, clG + ge);
        }
        float ccv[4];
        #pragma unroll
        for (int q = 0; q < 4; q++)
            ccv[q] = ccG[cbase + wc * 64 + q * 16 + l15];
        __syncthreads();   // drains vmcnt -> tile + ccv ready

        #pragma unroll 2
        for (int q = 0; q < 4; q++) {
            int ccol = wc * 64 + q * 16;
            int coderow = ccol + l15;
            f16x8 bh[2], bl[2];
            #pragma unroll
            for (int c = 0; c < 2; c++) {
                int byte = coderow * 128 + ((c * 64 + l4 * 16) ^ ((coderow & 7) << 4));
                bh[c] = *(const f16x8*)(chT + byte);
                bl[c] = *(const f16x8*)(clT + byte);
            }
            #pragma unroll
            for (int s = 0; s < 2; s++) {
                f32x4 acc = {0.f, 0.f, 0.f, 0.f};
                acc = MFMA16(ah[s][0], bh[0], acc);
                acc = MFMA16(ah[s][1], bh[1], acc);
                acc = MFMA16(ah[s][0], bl[0], acc);
                acc = MFMA16(ah[s][1], bl[1], acc);
                acc = MFMA16(al[s][0], bh[0], acc);
                acc = MFMA16(al[s][1], bh[1], acc);
                int code = cbase + ccol + l15;
                #pragma unroll
                for (int r = 0; r < 4; r++) {
                    float cand = fmaf(-2.0f, acc[r], ccv[q]);
                    if (cand < bd[s][r]) { bd[s][r] = cand; bix[s][r] = code; }
                }
            }
        }
        __syncthreads();   // compute done before next stage overwrites
    }

    // ---- reduce argmin across the 16 code-lanes, then across the 2 code-waves
    float* redd = (float*)sm;          // [64][2]
    int*   redi = (int*)(sm + 512);    // [64][2]
    int*   bidx = (int*)(sm + 1024);   // [64]
    #pragma unroll
    for (int s = 0; s < 2; s++)
        #pragma unroll
        for (int r = 0; r < 4; r++) {
            float d = bd[s][r];
            int   ix = bix[s][r];
            #pragma unroll
            for (int m = 1; m < 16; m <<= 1) {
                float od = __shfl_xor(d, m);
                int   oi = __shfl_xor(ix, m);
                if (od < d || (od == d && oi < ix)) { d = od; ix = oi; }
            }
            if (l15 == 0) {
                int rowloc = wr * 32 + s * 16 + l4 * 4 + r;
                redd[rowloc * 2 + wc] = d;
                redi[rowloc * 2 + wc] = ix;
            }
        }
    __syncthreads();
    if (tid < 64) {
        float d0 = redd[tid * 2 + 0], d1 = redd[tid * 2 + 1];
        int   i0 = redi[tid * 2 + 0], i1 = redi[tid * 2 + 1];
        int ix = (d1 < d0 || (d1 == d0 && i1 < i0)) ? i1 : i0;
        bidx[tid] = ix;
        out[OUT2 + rowbase + tid] = (float)ix;
    }
    __syncthreads();
    {   // gather cb32[best] -> chunk0 (z_q_st == z_q) and chunk3
        int r = tid >> 2, seg = tid & 3;
        int ix = bidx[r];
        const float* src = cb32 + (long)ix * DIM + seg * 16;
        float* o0 = out + (rowbase + r) * DIM + seg * 16;
        float* o3 = out + OUT3 + (rowbase + r) * DIM + seg * 16;
        #pragma unroll
        for (int i = 0; i < 16; i++) { float t = src[i]; o0[i] = t; o3[i] = t; }
    }
}

extern "C" void kernel_launch(void* const* d_in, const int* in_sizes, int n_in,
                              void* d_out, int out_size, void* d_ws, size_t ws_size,
                              hipStream_t stream) {
    const float* z   = (const float*)d_in[0];
    const float* w   = (const float*)d_in[1];
    const float* bnw = (const float*)d_in[2];
    const float* bnb = (const float*)d_in[3];
    float* out = (float*)d_out;
    char*  wsb = (char*)d_ws;

    k_bn1 <<<64,   256, 0, stream>>>(w, wsb);
    k_cb  <<<256,  256, 0, stream>>>(w, bnw, bnb, wsb);
    k_main<<<512,  256, 0, stream>>>(z, wsb, out);
}